// Round 11
// baseline (158.250 us; speedup 1.0000x reference)
//
#include <hip/hip_runtime.h>

#define IMG 65536   // 256*256
#define W 256
#define H 256

// d_ws layout:
//   ktab: 20 x 256 floats (truncated, renormalized composed kernels; tap j at [8+j]), bytes [0, 20480)
//   ord : 192 ints at byte 20480 (images sorted by t desc)
//   rtab: 20 ints at byte 21248 (truncated radius per t)
//   mid : 192*65536 floats at byte 32768 (intermediate H-pass output, if ws_size permits)

// One block per t-row: block tt independently recomputes base^{*tt} (exact same
// f64 op sequence as the old serial loop -> bit-identical taps), truncates,
// renormalizes, writes its ktab row. Block 0 writes the identity row and sorts.
__global__ __launch_bounds__(256) void init_kernel(const int* __restrict__ t,
                                                   float* __restrict__ ktab,
                                                   int* __restrict__ ord,
                                                   int* __restrict__ rtab) {
  __shared__ double cur[256];
  __shared__ double sc[256];    // prefix-sum scratch
  __shared__ double base[11];
  __shared__ int keys[192];
  __shared__ int sRmax;
  int tid = threadIdx.x;
  int tt = blockIdx.x;          // 0..19
  if (tid == 0) {
    double p[11];
    double s = 0.0;
    for (int i = 0; i < 11; ++i) {
      double xx = (double)(i - 5) * 0.5;       // x / SIGMA, SIGMA=2
      p[i] = exp(-0.5 * xx * xx);
      s += p[i];
    }
    for (int i = 0; i < 11; ++i) base[i] = (double)(float)(p[i] / s);  // match np float32 taps
  }
  __syncthreads();

  if (tt == 0) {
    // identity kernel row (t=0 safety) + rank-sort images by t desc
    ktab[tid] = (tid == 8) ? 1.0f : 0.0f;
    if (tid == 0) rtab[0] = 0;
    if (tid < 192) keys[tid] = min(max(t[tid / 3], 0), 19);
    __syncthreads();
    if (tid < 192) {
      int k = keys[tid];
      int rank = 0;
      for (int j = 0; j < 192; ++j) {
        int kj = keys[j];
        if (kj > k || (kj == k && j < tid)) ++rank;
      }
      ord[rank] = tid;
    }
    return;
  }

  cur[tid] = (tid < 11) ? base[tid] : 0.0;
  __syncthreads();
  for (int step = 2; step <= tt; ++step) {
    int Lprev = 10 * (step - 1) + 1;
    double a = 0.0;
    for (int i = 0; i < 11; ++i) {
      int jj = tid - i;
      if (jj >= 0 && jj < Lprev) a += base[i] * cur[jj];
    }
    __syncthreads();
    cur[tid] = a;
    __syncthreads();
  }
  // parallel inclusive prefix sum of cur -> sc (Hillis-Steele, 8 steps)
  sc[tid] = cur[tid];
  __syncthreads();
#pragma unroll
  for (int off = 1; off < 256; off <<= 1) {
    double tmp = (tid >= off) ? sc[tid - off] : 0.0;
    __syncthreads();
    sc[tid] += tmp;
    __syncthreads();
  }
  if (tid == 0) sRmax = 1;
  __syncthreads();
  // truncation: R = max r in [1,5t] with tail-outside-(r-1) > 1e-5  (monotone)
  int c = 5 * tt;
  double total = sc[255];
  if (tid >= 1 && tid <= c) {
    double Srm1 = sc[c + tid - 1] - sc[c - tid];     // window sum, radius tid-1
    if (total - Srm1 > 1e-5) atomicMax(&sRmax, tid);
  }
  __syncthreads();
  int Rk = sRmax;
  double ksum = sc[c + Rk] - ((c - Rk - 1 >= 0) ? sc[c - Rk - 1] : 0.0);
  double scale = 1.0 / ksum;                         // renormalize kept mass to 1
  if (tid == 0) rtab[tt] = Rk;
  int c0 = c - Rk;
  int Lk = 2 * Rk + 1;
  ktab[tt * 256 + tid] =
      (tid >= 8 && tid < 8 + Lk) ? (float)(cur[tid - 8 + c0] * scale) : 0.0f;
}

// H-pass: conv along h. Block = (16-wide w-tile) x (full 256 rows) of one image.
// LDS tile 256 rows x stride-17 (pad +1) = 17 KB -> 8 blocks/CU.
// Stores are sector-complete per instruction (16 lanes x 4 B = 64 B contiguous).
__global__ __launch_bounds__(256, 8) void hpass_kernel(const float* __restrict__ x,
                                                       const int* __restrict__ t,
                                                       const float* __restrict__ ktab,
                                                       const int* __restrict__ ord,
                                                       const int* __restrict__ rtab,
                                                       float* __restrict__ out) {
  __shared__ float tile[256 * 17];
  int tid = threadIdx.x;
  int img = __builtin_amdgcn_readfirstlane(ord[blockIdx.y]);
  int wt = blockIdx.x;                        // 0..15
  int b = img / 3;
  int tv = __builtin_amdgcn_readfirstlane(min(max(t[b], 0), 19));
  int R = __builtin_amdgcn_readfirstlane(rtab[tv]);
  int L = 2 * R + 1;
  const float* __restrict__ kt = ktab + tv * 256;   // SGPR base -> s_load taps
  const float* src = x + (size_t)img * IMG + (wt << 4);
  float* dst = out + (size_t)img * IMG + (wt << 4);
  {
    int c4 = (tid & 3) << 2;
    int r0 = tid >> 2;                        // 0..63
#pragma unroll
    for (int i = 0; i < 4; ++i) {
      int r = r0 + (i << 6);
      float4 v = *reinterpret_cast<const float4*>(src + r * W + c4);
      tile[r * 17 + c4 + 0] = v.x;
      tile[r * 17 + c4 + 1] = v.y;
      tile[r * 17 + c4 + 2] = v.z;
      tile[r * 17 + c4 + 3] = v.w;
    }
  }
  __syncthreads();
  int col = tid & 15;
  int rgrp = tid >> 4;                        // 0..15
  int nIter = (L + 30) & ~15;                 // >= L+15, multiple of 16; extra taps are zeros
  int h0 = rgrp << 4;
  float acc[16];
  float kq[16];
#pragma unroll
  for (int o = 0; o < 16; ++o) { acc[o] = 0.f; kq[o] = 0.f; }
  int pbase = h0 - R;
  for (int jb = 0; jb < nIter; jb += 16) {
    int p0 = pbase + jb;
    if (p0 >= 0 && p0 <= 240) {
      // interior fast path: sequential LDS addresses (offset immediates)
#pragma unroll
      for (int u = 0; u < 16; ++u) {
        kq[u] = kt[jb + u + 8];
        float v = tile[(p0 + u) * 17 + col];
#pragma unroll
        for (int o = 0; o < 16; ++o) acc[o] += kq[(u - o) & 15] * v;
      }
    } else {
#pragma unroll
      for (int u = 0; u < 16; ++u) {
        kq[u] = kt[jb + u + 8];
        int p = p0 + u;
        int rp = 255 - abs(255 - abs(p));     // reflect (single fold valid: |p| <= 510)
        float v = tile[rp * 17 + col];
#pragma unroll
        for (int o = 0; o < 16; ++o) acc[o] += kq[(u - o) & 15] * v;
      }
    }
  }
#pragma unroll
  for (int o = 0; o < 16; ++o) dst[(h0 + o) * W + col] = acc[o];
}

// W-pass (two-buffer): conv along w, src -> dst. Block = (16-row band) x (256 cols).
// LDS tile[16][256] word-XOR-swizzled (conflict-free conv reads); 8 blocks/CU.
// EPILOGUE FIX (round-10 diagnosis): the direct per-thread float4 stores made
// every store instruction scatter 64 x 16-B partial sectors -> L2 write-allocate
// cascade (WRITE_SIZE 328 MB vs 49 MB ideal, +50 MB RMW fetch). Now acc bounces
// through LDS and the store loop emits sector-complete instructions (each
// 16-lane row-group writes 64 B contiguous), matching hpass's clean pattern.
__global__ __launch_bounds__(256, 8) void wpass_split(const float* __restrict__ srcbuf,
                                                      const int* __restrict__ t,
                                                      const float* __restrict__ ktab,
                                                      const int* __restrict__ ord,
                                                      const int* __restrict__ rtab,
                                                      float* __restrict__ dstbuf) {
  __shared__ float tile[16 * 256];
  int tid = threadIdx.x;
  int img = __builtin_amdgcn_readfirstlane(ord[blockIdx.y]);
  int ht = blockIdx.x;                        // 0..15
  int b = img / 3;
  int tv = __builtin_amdgcn_readfirstlane(min(max(t[b], 0), 19));
  int R = __builtin_amdgcn_readfirstlane(rtab[tv]);
  int L = 2 * R + 1;
  const float* __restrict__ kt = ktab + tv * 256;   // SGPR base -> s_load taps
  const float* src = srcbuf + (size_t)img * IMG + (ht << 4) * W;
  float* dst = dstbuf + (size_t)img * IMG + (ht << 4) * W;
  {
    int r = tid >> 4;                         // 0..15
    int c4 = (tid & 15) << 2;
    int sw = r;                               // word-granular swizzle key
#pragma unroll
    for (int kk = 0; kk < 4; ++kk) {
      int c = c4 + (kk << 6);
      float4 v = *reinterpret_cast<const float4*>(src + r * W + c);
      tile[(r << 8) + ((c + 0) ^ sw)] = v.x;
      tile[(r << 8) + ((c + 1) ^ sw)] = v.y;
      tile[(r << 8) + ((c + 2) ^ sw)] = v.z;
      tile[(r << 8) + ((c + 3) ^ sw)] = v.w;
    }
  }
  __syncthreads();
  int row = tid & 15;
  int wgrp = tid >> 4;                        // 0..15
  int rowbase = row << 8;
  int sw = row;
  int nIter = (L + 30) & ~15;
  int w0 = wgrp << 4;
  float acc[16];
  float kq[16];
#pragma unroll
  for (int o = 0; o < 16; ++o) { acc[o] = 0.f; kq[o] = 0.f; }
  int pbase = w0 - R;
  for (int jb = 0; jb < nIter; jb += 16) {
    int p0 = pbase + jb;
    if (p0 >= 0 && p0 <= 240) {
#pragma unroll
      for (int u = 0; u < 16; ++u) {
        kq[u] = kt[jb + u + 8];
        float v = tile[rowbase + ((p0 + u) ^ sw)];
#pragma unroll
        for (int o = 0; o < 16; ++o) acc[o] += kq[(u - o) & 15] * v;
      }
    } else {
#pragma unroll
      for (int u = 0; u < 16; ++u) {
        kq[u] = kt[jb + u + 8];
        int p = p0 + u;
        int rp = 255 - abs(255 - abs(p));
        float v = tile[rowbase + (rp ^ sw)];
#pragma unroll
        for (int o = 0; o < 16; ++o) acc[o] += kq[(u - o) & 15] * v;
      }
    }
  }
  // ---- transpose epilogue: LDS round-trip -> sector-complete stores ----
  __syncthreads();                            // all conv reads of tile done
#pragma unroll
  for (int o = 0; o < 16; ++o)
    tile[rowbase + ((w0 + o) ^ sw)] = acc[o]; // banks: 2-way max (XOR by row)
  __syncthreads();
  {
    int r2 = tid >> 4;                        // 0..15
    int i2 = tid & 15;
#pragma unroll
    for (int k = 0; k < 4; ++k)
#pragma unroll
      for (int d = 0; d < 4; ++d) {
        // block-rotate by r2 so concurrent row-groups hit different bank halves
        int c = (k << 6) + (((d + r2) & 3) << 4) + i2;
        dst[r2 * W + c] = tile[(r2 << 8) + (c ^ r2)];
      }
  }
}

// Fallback in-place W-pass (exact round-7 config: 32-row band, 32 KB LDS,
// 4 blocks/CU -- the configuration measured safe for in-place traffic).
// Dead code in practice (ws_size check passes; kept for safety).
__global__ __launch_bounds__(256, 4) void wpass_inplace(const int* __restrict__ t,
                                                        const float* __restrict__ ktab,
                                                        const int* __restrict__ ord,
                                                        const int* __restrict__ rtab,
                                                        float* __restrict__ io) {
  __shared__ float tile[32 * 256];
  int tid = threadIdx.x;
  int img = __builtin_amdgcn_readfirstlane(ord[blockIdx.y]);
  int ht = blockIdx.x;                        // 0..7
  int b = img / 3;
  int tv = __builtin_amdgcn_readfirstlane(min(max(t[b], 0), 19));
  int R = __builtin_amdgcn_readfirstlane(rtab[tv]);
  int L = 2 * R + 1;
  const float* __restrict__ kt = ktab + tv * 256;
  float* base = io + (size_t)img * IMG + (ht << 5) * W;
  {
    int r = tid >> 3;                         // 0..31
    int c4 = (tid & 7) << 2;
    int sw = r;
#pragma unroll
    for (int kk = 0; kk < 8; ++kk) {
      int c = c4 + (kk << 5);
      float4 v = *reinterpret_cast<const float4*>(base + r * W + c);
      tile[(r << 8) + ((c + 0) ^ sw)] = v.x;
      tile[(r << 8) + ((c + 1) ^ sw)] = v.y;
      tile[(r << 8) + ((c + 2) ^ sw)] = v.z;
      tile[(r << 8) + ((c + 3) ^ sw)] = v.w;
    }
  }
  __syncthreads();
  int row = tid & 31;
  int wgrp = tid >> 5;                        // 0..7
  int rowbase = row << 8;
  int sw = row;
  int nIter = (L + 30) & ~15;
  for (int g = 0; g < 2; ++g) {
    int w0 = (wgrp << 5) + (g << 4);
    float acc[16];
    float kq[16];
#pragma unroll
    for (int o = 0; o < 16; ++o) { acc[o] = 0.f; kq[o] = 0.f; }
    int pbase = w0 - R;
    for (int jb = 0; jb < nIter; jb += 16) {
      int p0 = pbase + jb;
      if (p0 >= 0 && p0 <= 240) {
#pragma unroll
        for (int u = 0; u < 16; ++u) {
          kq[u] = kt[jb + u + 8];
          float v = tile[rowbase + ((p0 + u) ^ sw)];
#pragma unroll
          for (int o = 0; o < 16; ++o) acc[o] += kq[(u - o) & 15] * v;
        }
      } else {
#pragma unroll
        for (int u = 0; u < 16; ++u) {
          kq[u] = kt[jb + u + 8];
          int p = p0 + u;
          int rp = 255 - abs(255 - abs(p));
          float v = tile[rowbase + (rp ^ sw)];
#pragma unroll
          for (int o = 0; o < 16; ++o) acc[o] += kq[(u - o) & 15] * v;
        }
      }
    }
    float4 v0 = make_float4(acc[0], acc[1], acc[2], acc[3]);
    float4 v1 = make_float4(acc[4], acc[5], acc[6], acc[7]);
    float4 v2 = make_float4(acc[8], acc[9], acc[10], acc[11]);
    float4 v3 = make_float4(acc[12], acc[13], acc[14], acc[15]);
    float* o0 = base + row * W + w0;
    *reinterpret_cast<float4*>(o0 + 0) = v0;
    *reinterpret_cast<float4*>(o0 + 4) = v1;
    *reinterpret_cast<float4*>(o0 + 8) = v2;
    *reinterpret_cast<float4*>(o0 + 12) = v3;
  }
}

extern "C" void kernel_launch(void* const* d_in, const int* in_sizes, int n_in,
                              void* d_out, int out_size, void* d_ws, size_t ws_size,
                              hipStream_t stream) {
  const float* x = (const float*)d_in[0];
  const int* t = (const int*)d_in[1];
  float* out = (float*)d_out;
  float* ktab = (float*)d_ws;
  int* ord = (int*)((char*)d_ws + 20480);
  int* rtab = (int*)((char*)d_ws + 21248);
  const size_t mid_off = 32768;
  const size_t mid_bytes = (size_t)192 * IMG * 4;

  hipLaunchKernelGGL(init_kernel, dim3(20), dim3(256), 0, stream, t, ktab, ord, rtab);
  if (ws_size >= mid_off + mid_bytes) {
    float* mid = (float*)((char*)d_ws + mid_off);
    hipLaunchKernelGGL(hpass_kernel, dim3(16, 192), dim3(256), 0, stream, x, t, ktab, ord, rtab, mid);
    hipLaunchKernelGGL(wpass_split, dim3(16, 192), dim3(256), 0, stream, mid, t, ktab, ord, rtab, out);
  } else {
    hipLaunchKernelGGL(hpass_kernel, dim3(16, 192), dim3(256), 0, stream, x, t, ktab, ord, rtab, out);
    hipLaunchKernelGGL(wpass_inplace, dim3(8, 192), dim3(256), 0, stream, t, ktab, ord, rtab, out);
  }
}

// Round 12
// 96.431 us; speedup vs baseline: 1.6411x; 1.6411x over previous
//
#include <hip/hip_runtime.h>

#define IMG 65536   // 256*256
#define W 256
#define H 256

// d_ws layout:
//   ktab: 20 x 256 floats (truncated, renormalized composed kernels; tap j at [8+j]), bytes [0, 20480)
//   ord : 192 ints at byte 20480 (images sorted by t desc)
//   rtab: 20 ints at byte 21248 (truncated radius per t)
//   mid : 192*65536 floats at byte 32768 (intermediate H-pass output)

__global__ __launch_bounds__(256) void init_kernel(const int* __restrict__ t,
                                                   float* __restrict__ ktab,
                                                   int* __restrict__ ord,
                                                   int* __restrict__ rtab) {
  __shared__ double cur[256];
  __shared__ double sc[256];    // prefix-sum scratch
  __shared__ double base[11];
  __shared__ int keys[192];
  __shared__ int sRmax;
  int tid = threadIdx.x;
  int tt = blockIdx.x;          // 0..19
  if (tid == 0) {
    double p[11];
    double s = 0.0;
    for (int i = 0; i < 11; ++i) {
      double xx = (double)(i - 5) * 0.5;       // x / SIGMA, SIGMA=2
      p[i] = exp(-0.5 * xx * xx);
      s += p[i];
    }
    for (int i = 0; i < 11; ++i) base[i] = (double)(float)(p[i] / s);  // match np float32 taps
  }
  __syncthreads();

  if (tt == 0) {
    // identity kernel row (t=0 safety) + rank-sort images by t desc
    ktab[tid] = (tid == 8) ? 1.0f : 0.0f;
    if (tid == 0) rtab[0] = 0;
    if (tid < 192) keys[tid] = min(max(t[tid / 3], 0), 19);
    __syncthreads();
    if (tid < 192) {
      int k = keys[tid];
      int rank = 0;
      for (int j = 0; j < 192; ++j) {
        int kj = keys[j];
        if (kj > k || (kj == k && j < tid)) ++rank;
      }
      ord[rank] = tid;
    }
    return;
  }

  cur[tid] = (tid < 11) ? base[tid] : 0.0;
  __syncthreads();
  for (int step = 2; step <= tt; ++step) {
    int Lprev = 10 * (step - 1) + 1;
    double a = 0.0;
    for (int i = 0; i < 11; ++i) {
      int jj = tid - i;
      if (jj >= 0 && jj < Lprev) a += base[i] * cur[jj];
    }
    __syncthreads();
    cur[tid] = a;
    __syncthreads();
  }
  // parallel inclusive prefix sum of cur -> sc (Hillis-Steele, 8 steps)
  sc[tid] = cur[tid];
  __syncthreads();
#pragma unroll
  for (int off = 1; off < 256; off <<= 1) {
    double tmp = (tid >= off) ? sc[tid - off] : 0.0;
    __syncthreads();
    sc[tid] += tmp;
    __syncthreads();
  }
  if (tid == 0) sRmax = 1;
  __syncthreads();
  // truncation: R = max r in [1,5t] with tail-outside-(r-1) > 1e-5  (monotone)
  int c = 5 * tt;
  double total = sc[255];
  if (tid >= 1 && tid <= c) {
    double Srm1 = sc[c + tid - 1] - sc[c - tid];     // window sum, radius tid-1
    if (total - Srm1 > 1e-5) atomicMax(&sRmax, tid);
  }
  __syncthreads();
  int Rk = sRmax;
  double ksum = sc[c + Rk] - ((c - Rk - 1 >= 0) ? sc[c - Rk - 1] : 0.0);
  double scale = 1.0 / ksum;                         // renormalize kept mass to 1
  if (tid == 0) rtab[tt] = Rk;
  int c0 = c - Rk;
  int Lk = 2 * Rk + 1;
  ktab[tt * 256 + tid] =
      (tid >= 8 && tid < 8 + Lk) ? (float)(cur[tid - 8 + c0] * scale) : 0.0f;
}

// H-pass: conv along h. Block = (16-wide w-tile) x (full 256 rows) of one image.
// LDS tile 256 rows x stride-17 (pad +1) = 17 KB -> 8 blocks/CU.
// MEASURED CLEAN at this geometry (rounds 8-11: WRITE ~55 MB, FETCH ~54 MB).
__global__ __launch_bounds__(256, 8) void hpass_kernel(const float* __restrict__ x,
                                                       const int* __restrict__ t,
                                                       const float* __restrict__ ktab,
                                                       const int* __restrict__ ord,
                                                       const int* __restrict__ rtab,
                                                       float* __restrict__ out) {
  __shared__ float tile[256 * 17];
  int tid = threadIdx.x;
  int img = __builtin_amdgcn_readfirstlane(ord[blockIdx.y]);
  int wt = blockIdx.x;                        // 0..15
  int b = img / 3;
  int tv = __builtin_amdgcn_readfirstlane(min(max(t[b], 0), 19));
  int R = __builtin_amdgcn_readfirstlane(rtab[tv]);
  int L = 2 * R + 1;
  const float* __restrict__ kt = ktab + tv * 256;   // SGPR base -> s_load taps
  const float* src = x + (size_t)img * IMG + (wt << 4);
  float* dst = out + (size_t)img * IMG + (wt << 4);
  {
    int c4 = (tid & 3) << 2;
    int r0 = tid >> 2;                        // 0..63
#pragma unroll
    for (int i = 0; i < 4; ++i) {
      int r = r0 + (i << 6);
      float4 v = *reinterpret_cast<const float4*>(src + r * W + c4);
      tile[r * 17 + c4 + 0] = v.x;
      tile[r * 17 + c4 + 1] = v.y;
      tile[r * 17 + c4 + 2] = v.z;
      tile[r * 17 + c4 + 3] = v.w;
    }
  }
  __syncthreads();
  int col = tid & 15;
  int rgrp = tid >> 4;                        // 0..15
  int nIter = (L + 30) & ~15;                 // >= L+15, multiple of 16; extra taps are zeros
  int h0 = rgrp << 4;
  float acc[16];
  float kq[16];
#pragma unroll
  for (int o = 0; o < 16; ++o) { acc[o] = 0.f; kq[o] = 0.f; }
  int pbase = h0 - R;
  for (int jb = 0; jb < nIter; jb += 16) {
    int p0 = pbase + jb;
    if (p0 >= 0 && p0 <= 240) {
      // interior fast path: sequential LDS addresses (offset immediates)
#pragma unroll
      for (int u = 0; u < 16; ++u) {
        kq[u] = kt[jb + u + 8];
        float v = tile[(p0 + u) * 17 + col];
#pragma unroll
        for (int o = 0; o < 16; ++o) acc[o] += kq[(u - o) & 15] * v;
      }
    } else {
#pragma unroll
      for (int u = 0; u < 16; ++u) {
        kq[u] = kt[jb + u + 8];
        int p = p0 + u;
        int rp = 255 - abs(255 - abs(p));     // reflect (single fold valid: |p| <= 510)
        float v = tile[rp * 17 + col];
#pragma unroll
        for (int o = 0; o < 16; ++o) acc[o] += kq[(u - o) & 15] * v;
      }
    }
  }
#pragma unroll
  for (int o = 0; o < 16; ++o) dst[(h0 + o) * W + col] = acc[o];
}

// W-pass: EXACT round-7 geometry (measured clean: 45.9 us, WRITE 60.7 MB):
// 32-row band, tile[32][256] = 32 KB, launch_bounds(256,5), grid (8,192),
// word-XOR swizzle, float4 stores. Only change vs round 7: reads srcbuf (mid)
// instead of in-place io. The 16-row/(256,8) geometry is the measured-dirty
// regime (WRITE 328-366 MB, rounds 8/10/11) -- do not return to it.
__global__ __launch_bounds__(256, 5) void wpass_split(const float* __restrict__ srcbuf,
                                                      const int* __restrict__ t,
                                                      const float* __restrict__ ktab,
                                                      const int* __restrict__ ord,
                                                      const int* __restrict__ rtab,
                                                      float* __restrict__ dstbuf) {
  __shared__ float tile[32 * 256];
  int tid = threadIdx.x;
  int img = __builtin_amdgcn_readfirstlane(ord[blockIdx.y]);
  int ht = blockIdx.x;                        // 0..7
  int b = img / 3;
  int tv = __builtin_amdgcn_readfirstlane(min(max(t[b], 0), 19));
  int R = __builtin_amdgcn_readfirstlane(rtab[tv]);
  int L = 2 * R + 1;
  const float* __restrict__ kt = ktab + tv * 256;   // SGPR base -> s_load taps
  const float* src = srcbuf + (size_t)img * IMG + (ht << 5) * W;
  float* dst = dstbuf + (size_t)img * IMG + (ht << 5) * W;
  {
    int r = tid >> 3;                         // 0..31
    int c4 = (tid & 7) << 2;
    int sw = r;                               // word-granular swizzle key
#pragma unroll
    for (int kk = 0; kk < 8; ++kk) {
      int c = c4 + (kk << 5);
      float4 v = *reinterpret_cast<const float4*>(src + r * W + c);
      tile[(r << 8) + ((c + 0) ^ sw)] = v.x;
      tile[(r << 8) + ((c + 1) ^ sw)] = v.y;
      tile[(r << 8) + ((c + 2) ^ sw)] = v.z;
      tile[(r << 8) + ((c + 3) ^ sw)] = v.w;
    }
  }
  __syncthreads();
  int row = tid & 31;
  int wgrp = tid >> 5;                        // 0..7
  int rowbase = row << 8;
  int sw = row;
  int nIter = (L + 30) & ~15;
  for (int g = 0; g < 2; ++g) {
    int w0 = (wgrp << 5) + (g << 4);
    float acc[16];
    float kq[16];
#pragma unroll
    for (int o = 0; o < 16; ++o) { acc[o] = 0.f; kq[o] = 0.f; }
    int pbase = w0 - R;
    for (int jb = 0; jb < nIter; jb += 16) {
      int p0 = pbase + jb;
      if (p0 >= 0 && p0 <= 240) {
#pragma unroll
        for (int u = 0; u < 16; ++u) {
          kq[u] = kt[jb + u + 8];
          float v = tile[rowbase + ((p0 + u) ^ sw)];
#pragma unroll
          for (int o = 0; o < 16; ++o) acc[o] += kq[(u - o) & 15] * v;
        }
      } else {
#pragma unroll
        for (int u = 0; u < 16; ++u) {
          kq[u] = kt[jb + u + 8];
          int p = p0 + u;
          int rp = 255 - abs(255 - abs(p));
          float v = tile[rowbase + (rp ^ sw)];
#pragma unroll
          for (int o = 0; o < 16; ++o) acc[o] += kq[(u - o) & 15] * v;
        }
      }
    }
    float4 v0 = make_float4(acc[0], acc[1], acc[2], acc[3]);
    float4 v1 = make_float4(acc[4], acc[5], acc[6], acc[7]);
    float4 v2 = make_float4(acc[8], acc[9], acc[10], acc[11]);
    float4 v3 = make_float4(acc[12], acc[13], acc[14], acc[15]);
    float* o0 = dst + row * W + w0;
    *reinterpret_cast<float4*>(o0 + 0) = v0;
    *reinterpret_cast<float4*>(o0 + 4) = v1;
    *reinterpret_cast<float4*>(o0 + 8) = v2;
    *reinterpret_cast<float4*>(o0 + 12) = v3;
  }
}

// Fallback in-place W-pass (round-7 config, in-place on out) if ws is too small.
__global__ __launch_bounds__(256, 5) void wpass_inplace(const int* __restrict__ t,
                                                        const float* __restrict__ ktab,
                                                        const int* __restrict__ ord,
                                                        const int* __restrict__ rtab,
                                                        float* __restrict__ io) {
  __shared__ float tile[32 * 256];
  int tid = threadIdx.x;
  int img = __builtin_amdgcn_readfirstlane(ord[blockIdx.y]);
  int ht = blockIdx.x;                        // 0..7
  int b = img / 3;
  int tv = __builtin_amdgcn_readfirstlane(min(max(t[b], 0), 19));
  int R = __builtin_amdgcn_readfirstlane(rtab[tv]);
  int L = 2 * R + 1;
  const float* __restrict__ kt = ktab + tv * 256;
  float* base = io + (size_t)img * IMG + (ht << 5) * W;
  {
    int r = tid >> 3;                         // 0..31
    int c4 = (tid & 7) << 2;
    int sw = r;
#pragma unroll
    for (int kk = 0; kk < 8; ++kk) {
      int c = c4 + (kk << 5);
      float4 v = *reinterpret_cast<const float4*>(base + r * W + c);
      tile[(r << 8) + ((c + 0) ^ sw)] = v.x;
      tile[(r << 8) + ((c + 1) ^ sw)] = v.y;
      tile[(r << 8) + ((c + 2) ^ sw)] = v.z;
      tile[(r << 8) + ((c + 3) ^ sw)] = v.w;
    }
  }
  __syncthreads();
  int row = tid & 31;
  int wgrp = tid >> 5;                        // 0..7
  int rowbase = row << 8;
  int sw = row;
  int nIter = (L + 30) & ~15;
  for (int g = 0; g < 2; ++g) {
    int w0 = (wgrp << 5) + (g << 4);
    float acc[16];
    float kq[16];
#pragma unroll
    for (int o = 0; o < 16; ++o) { acc[o] = 0.f; kq[o] = 0.f; }
    int pbase = w0 - R;
    for (int jb = 0; jb < nIter; jb += 16) {
      int p0 = pbase + jb;
      if (p0 >= 0 && p0 <= 240) {
#pragma unroll
        for (int u = 0; u < 16; ++u) {
          kq[u] = kt[jb + u + 8];
          float v = tile[rowbase + ((p0 + u) ^ sw)];
#pragma unroll
          for (int o = 0; o < 16; ++o) acc[o] += kq[(u - o) & 15] * v;
        }
      } else {
#pragma unroll
        for (int u = 0; u < 16; ++u) {
          kq[u] = kt[jb + u + 8];
          int p = p0 + u;
          int rp = 255 - abs(255 - abs(p));
          float v = tile[rowbase + (rp ^ sw)];
#pragma unroll
          for (int o = 0; o < 16; ++o) acc[o] += kq[(u - o) & 15] * v;
        }
      }
    }
    float4 v0 = make_float4(acc[0], acc[1], acc[2], acc[3]);
    float4 v1 = make_float4(acc[4], acc[5], acc[6], acc[7]);
    float4 v2 = make_float4(acc[8], acc[9], acc[10], acc[11]);
    float4 v3 = make_float4(acc[12], acc[13], acc[14], acc[15]);
    float* o0 = base + row * W + w0;
    *reinterpret_cast<float4*>(o0 + 0) = v0;
    *reinterpret_cast<float4*>(o0 + 4) = v1;
    *reinterpret_cast<float4*>(o0 + 8) = v2;
    *reinterpret_cast<float4*>(o0 + 12) = v3;
  }
}

extern "C" void kernel_launch(void* const* d_in, const int* in_sizes, int n_in,
                              void* d_out, int out_size, void* d_ws, size_t ws_size,
                              hipStream_t stream) {
  const float* x = (const float*)d_in[0];
  const int* t = (const int*)d_in[1];
  float* out = (float*)d_out;
  float* ktab = (float*)d_ws;
  int* ord = (int*)((char*)d_ws + 20480);
  int* rtab = (int*)((char*)d_ws + 21248);
  const size_t mid_off = 32768;
  const size_t mid_bytes = (size_t)192 * IMG * 4;

  hipLaunchKernelGGL(init_kernel, dim3(20), dim3(256), 0, stream, t, ktab, ord, rtab);
  if (ws_size >= mid_off + mid_bytes) {
    float* mid = (float*)((char*)d_ws + mid_off);
    hipLaunchKernelGGL(hpass_kernel, dim3(16, 192), dim3(256), 0, stream, x, t, ktab, ord, rtab, mid);
    hipLaunchKernelGGL(wpass_split, dim3(8, 192), dim3(256), 0, stream, mid, t, ktab, ord, rtab, out);
  } else {
    hipLaunchKernelGGL(hpass_kernel, dim3(16, 192), dim3(256), 0, stream, x, t, ktab, ord, rtab, out);
    hipLaunchKernelGGL(wpass_inplace, dim3(8, 192), dim3(256), 0, stream, t, ktab, ord, rtab, out);
  }
}

// Round 13
// 84.492 us; speedup vs baseline: 1.8730x; 1.1413x over previous
//
#include <hip/hip_runtime.h>

#define IMG 65536   // 256*256
#define W 256
#define H 256
#define RMAX 40     // truncated radius cap (t=19 tail at 40: ~2.6e-6 < 1e-5 budget)

// d_ws layout:
//   ktab: 20 x 256 floats (truncated, renormalized composed kernels; tap j at [8+j]), bytes [0, 20480)
//   ord : 192 ints at byte 20480 (images sorted by t desc)
//   rtab: 20 ints at byte 21248 (truncated radius per t, <= RMAX)
//   mid : 192*65536 floats at byte 32768 (intermediate H-pass output)

__global__ __launch_bounds__(256) void init_kernel(const int* __restrict__ t,
                                                   float* __restrict__ ktab,
                                                   int* __restrict__ ord,
                                                   int* __restrict__ rtab) {
  __shared__ double cur[256];
  __shared__ double sc[256];    // prefix-sum scratch
  __shared__ double base[11];
  __shared__ int keys[192];
  __shared__ int sRmax;
  int tid = threadIdx.x;
  int tt = blockIdx.x;          // 0..19
  if (tid == 0) {
    double p[11];
    double s = 0.0;
    for (int i = 0; i < 11; ++i) {
      double xx = (double)(i - 5) * 0.5;       // x / SIGMA, SIGMA=2
      p[i] = exp(-0.5 * xx * xx);
      s += p[i];
    }
    for (int i = 0; i < 11; ++i) base[i] = (double)(float)(p[i] / s);  // match np float32 taps
  }
  __syncthreads();

  if (tt == 0) {
    // identity kernel row (t=0 safety) + rank-sort images by t desc
    ktab[tid] = (tid == 8) ? 1.0f : 0.0f;
    if (tid == 0) rtab[0] = 0;
    if (tid < 192) keys[tid] = min(max(t[tid / 3], 0), 19);
    __syncthreads();
    if (tid < 192) {
      int k = keys[tid];
      int rank = 0;
      for (int j = 0; j < 192; ++j) {
        int kj = keys[j];
        if (kj > k || (kj == k && j < tid)) ++rank;
      }
      ord[rank] = tid;
    }
    return;
  }

  cur[tid] = (tid < 11) ? base[tid] : 0.0;
  __syncthreads();
  for (int step = 2; step <= tt; ++step) {
    int Lprev = 10 * (step - 1) + 1;
    double a = 0.0;
    for (int i = 0; i < 11; ++i) {
      int jj = tid - i;
      if (jj >= 0 && jj < Lprev) a += base[i] * cur[jj];
    }
    __syncthreads();
    cur[tid] = a;
    __syncthreads();
  }
  // parallel inclusive prefix sum of cur -> sc (Hillis-Steele, 8 steps)
  sc[tid] = cur[tid];
  __syncthreads();
#pragma unroll
  for (int off = 1; off < 256; off <<= 1) {
    double tmp = (tid >= off) ? sc[tid - off] : 0.0;
    __syncthreads();
    sc[tid] += tmp;
    __syncthreads();
  }
  if (tid == 0) sRmax = 1;
  __syncthreads();
  // truncation: R = max r in [1,5t] with tail-outside-(r-1) > 1e-5  (monotone)
  int c = 5 * tt;
  double total = sc[255];
  if (tid >= 1 && tid <= c) {
    double Srm1 = sc[c + tid - 1] - sc[c - tid];     // window sum, radius tid-1
    if (total - Srm1 > 1e-5) atomicMax(&sRmax, tid);
  }
  __syncthreads();
  int Rk = min(sRmax, RMAX);                         // cap for staged-halo kernels
  double ksum = sc[c + Rk] - ((c - Rk - 1 >= 0) ? sc[c - Rk - 1] : 0.0);
  double scale = 1.0 / ksum;                         // renormalize kept mass to 1
  if (tid == 0) rtab[tt] = Rk;
  int c0 = c - Rk;
  int Lk = 2 * Rk + 1;
  ktab[tt * 256 + tid] =
      (tid >= 8 && tid < 8 + Lk) ? (float)(cur[tid - 8 + c0] * scale) : 0.0f;
}

// H-pass: conv along h. Block = (16-wide w-tile) x (full 256 rows) of one image.
// EXTENDED TILE: rows -RMAX..311 staged with reflection materialized (352 rows x
// stride 17 = 23.9 KB -> 6 blocks/CU). The conv loop is a single straight path:
// no interior/boundary branch (which was wave-DIVERGENT: rgrp varies in-wave ->
// both 16-FMA bodies ran exec-masked for most tap blocks = ~1.7x FMA waste),
// no per-read reflect math; read address advances 68 B per u -> ds offset imms.
__global__ __launch_bounds__(256, 6) void hpass_kernel(const float* __restrict__ x,
                                                       const int* __restrict__ t,
                                                       const float* __restrict__ ktab,
                                                       const int* __restrict__ ord,
                                                       const int* __restrict__ rtab,
                                                       float* __restrict__ out) {
  __shared__ float tile[352 * 17];
  int tid = threadIdx.x;
  int img = __builtin_amdgcn_readfirstlane(ord[blockIdx.y]);
  int wt = blockIdx.x;                        // 0..15
  int b = img / 3;
  int tv = __builtin_amdgcn_readfirstlane(min(max(t[b], 0), 19));
  int R = __builtin_amdgcn_readfirstlane(rtab[tv]);
  int L = 2 * R + 1;
  const float* __restrict__ kt = ktab + tv * 256;   // SGPR base -> s_load taps
  const float* src = x + (size_t)img * IMG + (wt << 4);
  float* dst = out + (size_t)img * IMG + (wt << 4);
  {
    int c4 = (tid & 3) << 2;
    int r0 = tid >> 2;                        // 0..63
#pragma unroll
    for (int i = 0; i < 6; ++i) {
      int rr = r0 + (i << 6);                 // 0..383
      if (rr < 352) {
        int p = rr - RMAX;                    // -40..311
        int srow = 255 - abs(255 - abs(p));   // reflect (valid for |p| <= 510)
        float4 v = *reinterpret_cast<const float4*>(src + srow * W + c4);
        tile[rr * 17 + c4 + 0] = v.x;
        tile[rr * 17 + c4 + 1] = v.y;
        tile[rr * 17 + c4 + 2] = v.z;
        tile[rr * 17 + c4 + 3] = v.w;
      }
    }
  }
  __syncthreads();
  int col = tid & 15;
  int rgrp = tid >> 4;                        // 0..15
  int nIter = (L + 30) & ~15;                 // >= L+15, multiple of 16; extra taps are zeros
  int h0 = rgrp << 4;
  float acc[16];
  float kq[16];
#pragma unroll
  for (int o = 0; o < 16; ++o) { acc[o] = 0.f; kq[o] = 0.f; }
  int pb = h0 - R + RMAX;                     // tile-row base (>= 0; reads <= 350 < 352)
  for (int jb = 0; jb < nIter; jb += 16) {
#pragma unroll
    for (int u = 0; u < 16; ++u) {
      kq[u] = kt[jb + u + 8];
      float v = tile[(pb + jb + u) * 17 + col];
#pragma unroll
      for (int o = 0; o < 16; ++o) acc[o] += kq[(u - o) & 15] * v;
    }
  }
#pragma unroll
  for (int o = 0; o < 16; ++o) dst[(h0 + o) * W + col] = acc[o];
}

// W-pass: conv along w, mid -> out. Block = (32-row band) x (256 cols), grid (8,192).
// EXTENDED TILE: cols -RMAX..315 staged reflected; stride 361 (361 mod 32 = 9,
// coprime) -> 32-lane same-col reads hit 32 distinct banks, XOR swizzle dropped.
// 46.2 KB LDS -> 3 blocks/CU: stays in the measured-clean (<=5/CU) store regime
// (the 16-row/8-per-CU geometry was the dirty 328-366 MB WRITE regime; avoid).
__global__ __launch_bounds__(256, 3) void wpass_split(const float* __restrict__ srcbuf,
                                                      const int* __restrict__ t,
                                                      const float* __restrict__ ktab,
                                                      const int* __restrict__ ord,
                                                      const int* __restrict__ rtab,
                                                      float* __restrict__ dstbuf) {
  __shared__ float tile[32 * 361];
  int tid = threadIdx.x;
  int img = __builtin_amdgcn_readfirstlane(ord[blockIdx.y]);
  int ht = blockIdx.x;                        // 0..7
  int b = img / 3;
  int tv = __builtin_amdgcn_readfirstlane(min(max(t[b], 0), 19));
  int R = __builtin_amdgcn_readfirstlane(rtab[tv]);
  int L = 2 * R + 1;
  const float* __restrict__ kt = ktab + tv * 256;   // SGPR base -> s_load taps
  const float* src = srcbuf + (size_t)img * IMG + (ht << 5) * W;
  float* dst = dstbuf + (size_t)img * IMG + (ht << 5) * W;
  {
    int srow = tid >> 3;                      // 0..31
    int jbase = tid & 7;
    const float* sp = src + srow * W;
    float* tp0 = &tile[srow * 361];
#pragma unroll
    for (int k = 0; k < 11; ++k) {
      int j = jbase + (k << 3);               // 0..87
      int c0 = -RMAX + (j << 2);              // -40..308
      float* tp = tp0 + c0 + RMAX;
      if (c0 >= 0 && c0 <= 252) {
        float4 v = *reinterpret_cast<const float4*>(sp + c0);
        tp[0] = v.x; tp[1] = v.y; tp[2] = v.z; tp[3] = v.w;
      } else {
#pragma unroll
        for (int d = 0; d < 4; ++d) {
          int cc = c0 + d;
          int rc = 255 - abs(255 - abs(cc));  // reflect
          tp[d] = sp[rc];
        }
      }
    }
  }
  __syncthreads();
  int row = tid & 31;
  int wgrp = tid >> 5;                        // 0..7
  int rowbase = row * 361;
  int nIter = (L + 30) & ~15;
  for (int g = 0; g < 2; ++g) {
    int w0 = (wgrp << 5) + (g << 4);
    float acc[16];
    float kq[16];
#pragma unroll
    for (int o = 0; o < 16; ++o) { acc[o] = 0.f; kq[o] = 0.f; }
    int pb = w0 - R + RMAX;                   // tile-col base (>= 0; reads <= 350 < 361)
    for (int jb = 0; jb < nIter; jb += 16) {
#pragma unroll
      for (int u = 0; u < 16; ++u) {
        kq[u] = kt[jb + u + 8];
        float v = tile[rowbase + pb + jb + u];
#pragma unroll
        for (int o = 0; o < 16; ++o) acc[o] += kq[(u - o) & 15] * v;
      }
    }
    float4 v0 = make_float4(acc[0], acc[1], acc[2], acc[3]);
    float4 v1 = make_float4(acc[4], acc[5], acc[6], acc[7]);
    float4 v2 = make_float4(acc[8], acc[9], acc[10], acc[11]);
    float4 v3 = make_float4(acc[12], acc[13], acc[14], acc[15]);
    float* o0 = dst + row * W + w0;
    *reinterpret_cast<float4*>(o0 + 0) = v0;
    *reinterpret_cast<float4*>(o0 + 4) = v1;
    *reinterpret_cast<float4*>(o0 + 8) = v2;
    *reinterpret_cast<float4*>(o0 + 12) = v3;
  }
}

// Fallback in-place W-pass (only if ws too small; same extended-tile structure).
__global__ __launch_bounds__(256, 3) void wpass_inplace(const int* __restrict__ t,
                                                        const float* __restrict__ ktab,
                                                        const int* __restrict__ ord,
                                                        const int* __restrict__ rtab,
                                                        float* __restrict__ io) {
  __shared__ float tile[32 * 361];
  int tid = threadIdx.x;
  int img = __builtin_amdgcn_readfirstlane(ord[blockIdx.y]);
  int ht = blockIdx.x;                        // 0..7
  int b = img / 3;
  int tv = __builtin_amdgcn_readfirstlane(min(max(t[b], 0), 19));
  int R = __builtin_amdgcn_readfirstlane(rtab[tv]);
  int L = 2 * R + 1;
  const float* __restrict__ kt = ktab + tv * 256;
  float* base = io + (size_t)img * IMG + (ht << 5) * W;
  {
    int srow = tid >> 3;
    int jbase = tid & 7;
    const float* sp = base + srow * W;
    float* tp0 = &tile[srow * 361];
#pragma unroll
    for (int k = 0; k < 11; ++k) {
      int j = jbase + (k << 3);
      int c0 = -RMAX + (j << 2);
      float* tp = tp0 + c0 + RMAX;
      if (c0 >= 0 && c0 <= 252) {
        float4 v = *reinterpret_cast<const float4*>(sp + c0);
        tp[0] = v.x; tp[1] = v.y; tp[2] = v.z; tp[3] = v.w;
      } else {
#pragma unroll
        for (int d = 0; d < 4; ++d) {
          int cc = c0 + d;
          int rc = 255 - abs(255 - abs(cc));
          tp[d] = sp[rc];
        }
      }
    }
  }
  __syncthreads();
  int row = tid & 31;
  int wgrp = tid >> 5;
  int rowbase = row * 361;
  int nIter = (L + 30) & ~15;
  for (int g = 0; g < 2; ++g) {
    int w0 = (wgrp << 5) + (g << 4);
    float acc[16];
    float kq[16];
#pragma unroll
    for (int o = 0; o < 16; ++o) { acc[o] = 0.f; kq[o] = 0.f; }
    int pb = w0 - R + RMAX;
    for (int jb = 0; jb < nIter; jb += 16) {
#pragma unroll
      for (int u = 0; u < 16; ++u) {
        kq[u] = kt[jb + u + 8];
        float v = tile[rowbase + pb + jb + u];
#pragma unroll
        for (int o = 0; o < 16; ++o) acc[o] += kq[(u - o) & 15] * v;
      }
    }
    float4 v0 = make_float4(acc[0], acc[1], acc[2], acc[3]);
    float4 v1 = make_float4(acc[4], acc[5], acc[6], acc[7]);
    float4 v2 = make_float4(acc[8], acc[9], acc[10], acc[11]);
    float4 v3 = make_float4(acc[12], acc[13], acc[14], acc[15]);
    float* o0 = base + row * W + w0;
    *reinterpret_cast<float4*>(o0 + 0) = v0;
    *reinterpret_cast<float4*>(o0 + 4) = v1;
    *reinterpret_cast<float4*>(o0 + 8) = v2;
    *reinterpret_cast<float4*>(o0 + 12) = v3;
  }
}

extern "C" void kernel_launch(void* const* d_in, const int* in_sizes, int n_in,
                              void* d_out, int out_size, void* d_ws, size_t ws_size,
                              hipStream_t stream) {
  const float* x = (const float*)d_in[0];
  const int* t = (const int*)d_in[1];
  float* out = (float*)d_out;
  float* ktab = (float*)d_ws;
  int* ord = (int*)((char*)d_ws + 20480);
  int* rtab = (int*)((char*)d_ws + 21248);
  const size_t mid_off = 32768;
  const size_t mid_bytes = (size_t)192 * IMG * 4;

  hipLaunchKernelGGL(init_kernel, dim3(20), dim3(256), 0, stream, t, ktab, ord, rtab);
  if (ws_size >= mid_off + mid_bytes) {
    float* mid = (float*)((char*)d_ws + mid_off);
    hipLaunchKernelGGL(hpass_kernel, dim3(16, 192), dim3(256), 0, stream, x, t, ktab, ord, rtab, mid);
    hipLaunchKernelGGL(wpass_split, dim3(8, 192), dim3(256), 0, stream, mid, t, ktab, ord, rtab, out);
  } else {
    hipLaunchKernelGGL(hpass_kernel, dim3(16, 192), dim3(256), 0, stream, x, t, ktab, ord, rtab, out);
    hipLaunchKernelGGL(wpass_inplace, dim3(8, 192), dim3(256), 0, stream, t, ktab, ord, rtab, out);
  }
}